// Round 1
// baseline (3145.658 us; speedup 1.0000x reference)
//
#include <hip/hip_runtime.h>

#define MB      16      // samples per block
#define BLOCK   256
#define HDIM    128
#define DDIM    16
#define NOBJ    6
#define NNODES  63

struct NodeTab {
    unsigned char obj[NNODES];    // element appended at this node (== max of subset)
    unsigned char depth[NNODES];  // subset size (1..6)
};

__device__ __forceinline__ float fsigmoid(float x) {
    return 1.0f / (1.0f + __expf(-x));
}
__device__ __forceinline__ float ftanh(float x) {
    x = fminf(15.0f, fmaxf(-15.0f, x));
    float e = __expf(2.0f * x);
    return (e - 1.0f) / (e + 1.0f);
}

__global__ __launch_bounds__(BLOCK, 2)
void subset_lstm_head_kernel(
    const float* __restrict__ x_input,  // [mb][6][16]
    const float* __restrict__ W_ih,     // [512][16]
    const float* __restrict__ W_hh,     // [512][128]
    const float* __restrict__ b_ih,     // [512]
    const float* __restrict__ b_hh,     // [512]
    const float* __restrict__ fc1_W,    // [256][128]
    const float* __restrict__ fc1_b,    // [256]
    const float* __restrict__ fc2_W,    // [10][256]
    const float* __restrict__ fc2_b,    // [10]
    float* __restrict__ out,            // [mb][10]
    NodeTab tab)
{
    __shared__ float s_x[MB * NOBJ * DDIM];   // 6 KB
    __shared__ float s_maxh[MB * HDIM];       // 8 KB
    __shared__ float s_h[6 * MB * HDIM];      // 48 KB  (DFS h stack, slot-major)
    float* s_fc1   = s_h;   // [MB][256] alias, used after LSTM phase
    float* s_logit = s_x;   // [MB][10]  alias, used after LSTM phase

    const int t = threadIdx.x;
    const int s_base = blockIdx.x * MB;

    for (int idx = t; idx < MB * NOBJ * DDIM; idx += BLOCK)
        s_x[idx] = x_input[s_base * NOBJ * DDIM + idx];
    for (int idx = t; idx < MB * HDIM; idx += BLOCK)
        s_maxh[idx] = -1e30f;

    const int c  = t & (HDIM - 1);  // hidden channel 0..127
    const int sg = t >> 7;          // sample half 0/1 (8 samples each)

    float bias[4];
    #pragma unroll
    for (int g = 0; g < 4; ++g)
        bias[g] = b_ih[g * HDIM + c] + b_hh[g * HDIM + c];

    float cst[5][8];  // c-state stack, statically indexed only

    for (int n = 0; n < NNODES; ++n) {
        __syncthreads();
        const int j = tab.obj[n];
        const int d = tab.depth[n];

        float acc[4][8];
        #pragma unroll
        for (int g = 0; g < 4; ++g)
            #pragma unroll
            for (int i = 0; i < 8; ++i)
                acc[g][i] = bias[g];

        // x contribution: z += W_ih @ x_j   (K = 16)
        #pragma unroll
        for (int k4 = 0; k4 < DDIM / 4; ++k4) {
            float4 w[4];
            #pragma unroll
            for (int g = 0; g < 4; ++g)
                w[g] = *(const float4*)&W_ih[(g * HDIM + c) * DDIM + k4 * 4];
            #pragma unroll
            for (int i = 0; i < 8; ++i) {
                const int s = sg * 8 + i;
                const float4 xv = *(const float4*)&s_x[(s * NOBJ + j) * DDIM + k4 * 4];
                #pragma unroll
                for (int g = 0; g < 4; ++g)
                    acc[g][i] += w[g].x * xv.x + w[g].y * xv.y + w[g].z * xv.z + w[g].w * xv.w;
            }
        }

        // h contribution: z += W_hh @ h_parent   (K = 128)
        if (d >= 2) {
            const float* hp = &s_h[(d - 2) * MB * HDIM];
            for (int k4 = 0; k4 < HDIM / 4; ++k4) {
                float4 w[4];
                #pragma unroll
                for (int g = 0; g < 4; ++g)
                    w[g] = *(const float4*)&W_hh[(g * HDIM + c) * HDIM + k4 * 4];
                #pragma unroll
                for (int i = 0; i < 8; ++i) {
                    const int s = sg * 8 + i;
                    const float4 hv = *(const float4*)&hp[s * HDIM + k4 * 4];
                    #pragma unroll
                    for (int g = 0; g < 4; ++g)
                        acc[g][i] += w[g].x * hv.x + w[g].y * hv.y + w[g].z * hv.z + w[g].w * hv.w;
                }
            }
        }

        // previous cell state (0 at depth 1), static-index select to stay in VGPRs
        float cprev[8];
        #pragma unroll
        for (int i = 0; i < 8; ++i) cprev[i] = 0.0f;
        #pragma unroll
        for (int sl = 0; sl < 5; ++sl)
            if (d - 2 == sl)
                #pragma unroll
                for (int i = 0; i < 8; ++i) cprev[i] = cst[sl][i];

        const int slot = d - 1;
        float cn_a[8];
        #pragma unroll
        for (int i = 0; i < 8; ++i) {
            const int s = sg * 8 + i;
            const float ig = fsigmoid(acc[0][i]);
            const float fg = fsigmoid(acc[1][i]);
            const float gg = ftanh(acc[2][i]);
            const float og = fsigmoid(acc[3][i]);
            const float cn = fg * cprev[i] + ig * gg;
            const float hn = og * ftanh(cn);
            cn_a[i] = cn;
            s_h[(slot * MB + s) * HDIM + c] = hn;
            s_maxh[s * HDIM + c] = fmaxf(s_maxh[s * HDIM + c], hn);
        }
        #pragma unroll
        for (int sl = 0; sl < 5; ++sl)
            if (slot == sl)
                #pragma unroll
                for (int i = 0; i < 8; ++i) cst[sl][i] = cn_a[i];
    }

    __syncthreads();

    // FC1: thread t owns feature f = t (0..255) for all 16 samples
    {
        const int f = t;
        float a1[MB];
        #pragma unroll
        for (int s = 0; s < MB; ++s) a1[s] = fc1_b[f];
        for (int k4 = 0; k4 < HDIM / 4; ++k4) {
            const float4 w = *(const float4*)&fc1_W[f * HDIM + k4 * 4];
            #pragma unroll
            for (int s = 0; s < MB; ++s) {
                const float4 h4 = *(const float4*)&s_maxh[s * HDIM + k4 * 4];
                a1[s] += w.x * h4.x + w.y * h4.y + w.z * h4.z + w.w * h4.w;
            }
        }
        #pragma unroll
        for (int s = 0; s < MB; ++s)
            s_fc1[s * 256 + f] = fmaxf(a1[s], 0.0f);
    }
    __syncthreads();

    // FC2: threads 0..159, (sample, action)
    if (t < MB * 10) {
        const int s = t / 10, a = t % 10;
        float acc2 = fc2_b[a];
        for (int f4 = 0; f4 < 256 / 4; ++f4) {
            const float4 w = *(const float4*)&fc2_W[a * 256 + f4 * 4];
            const float4 v = *(const float4*)&s_fc1[s * 256 + f4 * 4];
            acc2 += w.x * v.x + w.y * v.y + w.z * v.z + w.w * v.w;
        }
        s_logit[s * 10 + a] = acc2;
    }
    __syncthreads();

    // log_softmax: one thread per sample
    if (t < MB) {
        float m = -1e30f;
        #pragma unroll
        for (int a = 0; a < 10; ++a) m = fmaxf(m, s_logit[t * 10 + a]);
        float sum = 0.0f;
        #pragma unroll
        for (int a = 0; a < 10; ++a) sum += __expf(s_logit[t * 10 + a] - m);
        const float lse = m + __logf(sum);
        #pragma unroll
        for (int a = 0; a < 10; ++a)
            out[(s_base + t) * 10 + a] = s_logit[t * 10 + a] - lse;
    }
}

static void dfs_fill(NodeTab& tb, int& n, int maxel, int depth) {
    for (int j = maxel + 1; j < NOBJ; ++j) {
        tb.obj[n]   = (unsigned char)j;
        tb.depth[n] = (unsigned char)depth;
        ++n;
        dfs_fill(tb, n, j, depth + 1);
    }
}

extern "C" void kernel_launch(void* const* d_in, const int* in_sizes, int n_in,
                              void* d_out, int out_size, void* d_ws, size_t ws_size,
                              hipStream_t stream)
{
    (void)d_ws; (void)ws_size; (void)n_in; (void)out_size;

    NodeTab tab;
    int n = 0;
    dfs_fill(tab, n, -1, 1);   // 63 nodes, preorder DFS over sorted subsets

    const float* x    = (const float*)d_in[0];
    const float* Wih  = (const float*)d_in[1];
    const float* Whh  = (const float*)d_in[2];
    const float* bih  = (const float*)d_in[3];
    const float* bhh  = (const float*)d_in[4];
    const float* f1w  = (const float*)d_in[5];
    const float* f1b  = (const float*)d_in[6];
    const float* f2w  = (const float*)d_in[7];
    const float* f2b  = (const float*)d_in[8];

    const int mb = in_sizes[0] / (NOBJ * DDIM);   // 8192
    dim3 grid(mb / MB), block(BLOCK);
    subset_lstm_head_kernel<<<grid, block, 0, stream>>>(
        x, Wih, Whh, bih, bhh, f1w, f1b, f2w, f2b, (float*)d_out, tab);
}

// Round 2
// 363.425 us; speedup vs baseline: 8.6556x; 8.6556x over previous
//
#include <hip/hip_runtime.h>
#include <hip/hip_bf16.h>

#define BLOCK   512     // 8 waves
#define NSAMP   16      // samples per block (= N of the per-node GEMM)
#define HDIM    128
#define DDIM    16
#define NOBJ    6
#define NNODES  63

typedef __attribute__((ext_vector_type(8))) short bf16x8;
typedef __attribute__((ext_vector_type(4))) float f32x4;

struct NodeTab {
    unsigned char obj[NNODES];
    unsigned char depth[NNODES];
};

__device__ __forceinline__ float fsigmoid(float x) {
    return 1.0f / (1.0f + __expf(-x));
}
__device__ __forceinline__ float ftanh(float x) {
    x = fminf(15.0f, fmaxf(-15.0f, x));
    float e = __expf(2.0f * x);
    return (e - 1.0f) / (e + 1.0f);
}
__device__ __forceinline__ unsigned short f2bf(float x) {
    union { float f; unsigned int u; } a; a.f = x;
    unsigned int r = (a.u + 0x7FFFu + ((a.u >> 16) & 1u)) >> 16;
    return (unsigned short)r;
}

// LDS h-stack layout: element hs[((slot*16 + kslot)*16 + n)*8 + j] = h[k = kslot*8+j][n]
// B-fragment for chunk q, lane (quad,n): 8 elems at kslot = q*4+quad  -> 16B aligned.

__global__ __launch_bounds__(BLOCK, 2)
void subset_lstm_mfma_kernel(
    const float* __restrict__ x_input,  // [mb][6][16]
    const float* __restrict__ W_ih,     // [512][16]
    const float* __restrict__ W_hh,     // [512][128]
    const float* __restrict__ b_ih,     // [512]
    const float* __restrict__ b_hh,     // [512]
    const float* __restrict__ fc1_W,    // [256][128]
    const float* __restrict__ fc1_b,    // [256]
    const float* __restrict__ fc2_W,    // [10][256]
    const float* __restrict__ fc2_b,    // [10]
    float* __restrict__ out,            // [mb][10]
    NodeTab tab)
{
    __shared__ __align__(16) unsigned short hs[6 * 16 * NSAMP * 8];   // 24 KB
    __shared__ __align__(16) unsigned short xb[NOBJ * 4 * NSAMP * 8]; // 6 KB
    __shared__ float s_maxh[NSAMP * HDIM];                            // 8 KB
    __shared__ float s_fc1[NSAMP * 256];                              // 16 KB
    __shared__ float s_logit[NSAMP * 10];

    const int t      = threadIdx.x;
    const int w      = t >> 6;        // wave 0..7: owns channels w*16..w*16+15
    const int lane   = t & 63;
    const int quad   = lane >> 4;     // 0..3
    const int m16    = lane & 15;     // A-row within tile / B,D column (sample)
    const int s_base = blockIdx.x * NSAMP;

    // ---- build x B-chunks in LDS: xb[obj][quad'][n][j]; quads 2,3 = zero pad ----
    for (int idx = t; idx < NOBJ * 2 * NSAMP * 8; idx += BLOCK) {
        const int j   = idx & 7;
        const int n   = (idx >> 3) & 15;
        const int q   = (idx >> 7) & 1;
        const int obj = idx >> 8;
        xb[((obj * 4 + q) * NSAMP + n) * 8 + j] =
            f2bf(x_input[(s_base + n) * (NOBJ * DDIM) + obj * DDIM + q * 8 + j]);
        xb[((obj * 4 + 2 + q) * NSAMP + n) * 8 + j] = 0;
    }

    // ---- load persistent weight A-fragments: wf[gate][kchunk] ----
    // A[m = lane&15][k = quad*8+j]; row r = g*128 + w*16 + m16
    bf16x8 wf[4][5];
    #pragma unroll
    for (int g = 0; g < 4; ++g) {
        const int r = g * HDIM + w * 16 + m16;
        const float* whr = W_hh + r * HDIM;
        const float* wir = W_ih + r * DDIM;
        #pragma unroll
        for (int q = 0; q < 4; ++q) {
            union { unsigned short u[8]; bf16x8 v; } pk;
            #pragma unroll
            for (int j = 0; j < 8; ++j)
                pk.u[j] = f2bf(whr[q * 32 + quad * 8 + j]);
            wf[g][q] = pk.v;
        }
        {
            union { unsigned short u[8]; bf16x8 v; } pk;
            #pragma unroll
            for (int j = 0; j < 8; ++j) {
                float v = 0.0f;
                if (quad == 0) v = wir[j];
                else if (quad == 1) v = wir[8 + j];
                pk.u[j] = f2bf(v);
            }
            wf[g][4] = pk.v;
        }
    }

    // bias per D-row: row-in-tile = quad*4 + reg, channel c = w*16 + quad*4 + reg
    float bias[4][4];
    #pragma unroll
    for (int g = 0; g < 4; ++g)
        #pragma unroll
        for (int r = 0; r < 4; ++r) {
            const int c = w * 16 + quad * 4 + r;
            bias[g][r] = b_ih[g * HDIM + c] + b_hh[g * HDIM + c];
        }

    float cst[5][4];       // c stack (registers, static-indexed)
    float mh[4] = {-1e30f, -1e30f, -1e30f, -1e30f};

    for (int nd = 0; nd < NNODES; ++nd) {
        __syncthreads();
        const int jo = tab.obj[nd];
        const int d  = tab.depth[nd];

        f32x4 acc[4];
        #pragma unroll
        for (int g = 0; g < 4; ++g)
            acc[g] = f32x4{bias[g][0], bias[g][1], bias[g][2], bias[g][3]};

        if (d >= 2) {                       // h-parent contribution, K-chunks 0..3
            const int slot = d - 2;
            #pragma unroll
            for (int q = 0; q < 4; ++q) {
                const bf16x8 bfrag = *(const bf16x8*)
                    &hs[(((slot * 16) + q * 4 + quad) * NSAMP + m16) * 8];
                #pragma unroll
                for (int g = 0; g < 4; ++g)
                    acc[g] = __builtin_amdgcn_mfma_f32_16x16x32_bf16(
                        wf[g][q], bfrag, acc[g], 0, 0, 0);
            }
        }
        {                                    // x contribution, K-chunk 4
            const bf16x8 bfrag = *(const bf16x8*)
                &xb[((jo * 4 + quad) * NSAMP + m16) * 8];
            #pragma unroll
            for (int g = 0; g < 4; ++g)
                acc[g] = __builtin_amdgcn_mfma_f32_16x16x32_bf16(
                    wf[g][4], bfrag, acc[g], 0, 0, 0);
        }

        // ---- pointwise gates; lane owns channels c = w*16 + quad*4 + r, sample n = m16
        float cprev[4] = {0.f, 0.f, 0.f, 0.f};
        #pragma unroll
        for (int sl = 0; sl < 5; ++sl)
            if (d - 2 == sl)
                #pragma unroll
                for (int r = 0; r < 4; ++r) cprev[r] = cst[sl][r];

        float hn[4], cn_a[4];
        #pragma unroll
        for (int r = 0; r < 4; ++r) {
            const float ig = fsigmoid(acc[0][r]);
            const float fg = fsigmoid(acc[1][r]);
            const float gg = ftanh(acc[2][r]);
            const float og = fsigmoid(acc[3][r]);
            const float cn = fg * cprev[r] + ig * gg;
            const float h  = og * ftanh(cn);
            cn_a[r] = cn; hn[r] = h;
            mh[r] = fmaxf(mh[r], h);
        }
        #pragma unroll
        for (int sl = 0; sl < 5; ++sl)
            if (d - 1 == sl)
                #pragma unroll
                for (int r = 0; r < 4; ++r) cst[sl][r] = cn_a[r];

        // ---- write h into B-layout stack slot d-1 (4 consecutive j -> one 8B store)
        union { unsigned short u[4]; uint2 v; } hp;
        #pragma unroll
        for (int r = 0; r < 4; ++r) hp.u[r] = f2bf(hn[r]);
        const int kslot = w * 2 + (quad >> 1);
        unsigned short* dst =
            &hs[((((d - 1) * 16) + kslot) * NSAMP + m16) * 8 + (quad & 1) * 4];
        *(uint2*)dst = hp.v;
    }

    __syncthreads();
    // running max h -> LDS [n][c]
    #pragma unroll
    for (int r = 0; r < 4; ++r) {
        const int c = w * 16 + quad * 4 + r;
        s_maxh[m16 * HDIM + c] = mh[r];
    }
    __syncthreads();

    // ---- FC1: threads 0..255, feature f for all 16 samples ----
    if (t < 256) {
        const int f = t;
        float a1[NSAMP];
        #pragma unroll
        for (int s = 0; s < NSAMP; ++s) a1[s] = fc1_b[f];
        for (int k4 = 0; k4 < HDIM / 4; ++k4) {
            const float4 wv = *(const float4*)&fc1_W[f * HDIM + k4 * 4];
            #pragma unroll
            for (int s = 0; s < NSAMP; ++s) {
                const float4 h4 = *(const float4*)&s_maxh[s * HDIM + k4 * 4];
                a1[s] += wv.x * h4.x + wv.y * h4.y + wv.z * h4.z + wv.w * h4.w;
            }
        }
        #pragma unroll
        for (int s = 0; s < NSAMP; ++s)
            s_fc1[s * 256 + f] = fmaxf(a1[s], 0.0f);
    }
    __syncthreads();

    // ---- FC2: threads 0..159 ----
    if (t < NSAMP * 10) {
        const int s = t / 10, a = t % 10;
        float acc2 = fc2_b[a];
        for (int f4 = 0; f4 < 256 / 4; ++f4) {
            const float4 wv = *(const float4*)&fc2_W[a * 256 + f4 * 4];
            const float4 v  = *(const float4*)&s_fc1[s * 256 + f4 * 4];
            acc2 += wv.x * v.x + wv.y * v.y + wv.z * v.z + wv.w * v.w;
        }
        s_logit[s * 10 + a] = acc2;
    }
    __syncthreads();

    // ---- log_softmax ----
    if (t < NSAMP) {
        float m = -1e30f;
        #pragma unroll
        for (int a = 0; a < 10; ++a) m = fmaxf(m, s_logit[t * 10 + a]);
        float sum = 0.0f;
        #pragma unroll
        for (int a = 0; a < 10; ++a) sum += __expf(s_logit[t * 10 + a] - m);
        const float lse = m + __logf(sum);
        #pragma unroll
        for (int a = 0; a < 10; ++a)
            out[(s_base + t) * 10 + a] = s_logit[t * 10 + a] - lse;
    }
}

static void dfs_fill(NodeTab& tb, int& n, int maxel, int depth) {
    for (int j = maxel + 1; j < NOBJ; ++j) {
        tb.obj[n]   = (unsigned char)j;
        tb.depth[n] = (unsigned char)depth;
        ++n;
        dfs_fill(tb, n, j, depth + 1);
    }
}

extern "C" void kernel_launch(void* const* d_in, const int* in_sizes, int n_in,
                              void* d_out, int out_size, void* d_ws, size_t ws_size,
                              hipStream_t stream)
{
    (void)d_ws; (void)ws_size; (void)n_in; (void)out_size;

    NodeTab tab;
    int n = 0;
    dfs_fill(tab, n, -1, 1);   // 63 preorder DFS nodes over sorted subsets

    const float* x   = (const float*)d_in[0];
    const float* Wih = (const float*)d_in[1];
    const float* Whh = (const float*)d_in[2];
    const float* bih = (const float*)d_in[3];
    const float* bhh = (const float*)d_in[4];
    const float* f1w = (const float*)d_in[5];
    const float* f1b = (const float*)d_in[6];
    const float* f2w = (const float*)d_in[7];
    const float* f2b = (const float*)d_in[8];

    const int mb = in_sizes[0] / (NOBJ * DDIM);   // 8192
    dim3 grid(mb / NSAMP), block(BLOCK);
    subset_lstm_mfma_kernel<<<grid, block, 0, stream>>>(
        x, Wih, Whh, bih, bhh, f1w, f1b, f2w, f2b, (float*)d_out, tab);
}